// Round 7
// baseline (133.647 us; speedup 1.0000x reference)
//
#include <hip/hip_runtime.h>

// B=32, C=128, H=W=32, kern=2 -> pooled h=w=16
// out = B * sum_{i,c,h,w} [ log(mean_j dA(i,j)+eps) - log(mean_j dB(i,j)+eps) ]
//
// Params per (j,pixel,side): {s, s*mu}, s = sqrt(log2e/2)*rsqrt(v).
//   d_j = (s_j/k) * exp2(-(s_j*z - s_j*mu_j)^2),  k = sqrt(log2e/2)
// per j-term: fma, mul, exp2(neg-mod), fma = 3 VALU + 1 trans, 8B LDS.
// 1/(32k) = 0.036794063 folds into the post-sum scale.
//
// 2-tile software pipeline (grid 2048, 8 blocks/CU, fully resident):
//   load tile0 -> params buf0 -> ISSUE tile1 loads -> barrier ->
//   phase2(buf0) [tile1 L3 latency hides here] -> params buf1 -> barrier ->
//   phase2(buf1).  Inputs are L3-resident (restored just before launch), so
//   phase 1 is L3-latency/BW, not HBM.
//
// LDS per buffer (floats, BUFW=1648): Qside0 @ wl*68, Qside1 @ 548+wl*68
//   (548 = +4-bank skew so the half-wave b128 address pair hits disjoint
//   banks), z @ 1096 + b*17 + wl (17-stride: conflict-free i-gather).

#define GKL_EPS 1e-6f
#define BUFW 1648

struct TR { float2 m0, m1, l0, l1, n0, n1, k0, k1; float ev; };

__device__ __forceinline__ void tile_load(TR& r,
    const float* __restrict__ muA, const float* __restrict__ lvA,
    const float* __restrict__ muB, const float* __restrict__ lvB,
    const float* __restrict__ eps, int b, int c, int h, int w)
{
    const int base = ((b*128 + c)*32 + 2*h)*32 + 2*w;
    r.m0 = *(const float2*)(muA + base);
    r.m1 = *(const float2*)(muA + base + 32);
    r.l0 = *(const float2*)(lvA + base);
    r.l1 = *(const float2*)(lvA + base + 32);
    r.n0 = *(const float2*)(muB + base);
    r.n1 = *(const float2*)(muB + base + 32);
    r.k0 = *(const float2*)(lvB + base);
    r.k1 = *(const float2*)(lvB + base + 32);
    r.ev = eps[((b*128 + c)*16 + h)*16 + w];
}

__device__ __forceinline__ void tile_params(const TR& r, float* shb, int b, int wl)
{
    float mu  = (r.m0.x + r.m0.y + r.m1.x + r.m1.y) * 0.25f;
    float var = (__expf(r.l0.x)+__expf(r.l0.y)+__expf(r.l1.x)+__expf(r.l1.y)) * 0.0625f;
    float rs  = __builtin_amdgcn_rsqf(var);
    float s   = 0.84932185f * rs;                       // sqrt(log2e/2)/sqrt(v)
    *(float2*)(shb + wl*68 + 2*b) = make_float2(s, s*mu);
    shb[1096 + b*17 + wl] = fmaf(var*rs, r.ev, mu);     // z = mu + sqrt(v)*eps

    float mub  = (r.n0.x + r.n0.y + r.n1.x + r.n1.y) * 0.25f;
    float varb = (__expf(r.k0.x)+__expf(r.k0.y)+__expf(r.k1.x)+__expf(r.k1.y)) * 0.0625f;
    float rsb  = __builtin_amdgcn_rsqf(varb);
    float sb   = 0.84932185f * rsb;
    *(float2*)(shb + 548 + wl*68 + 2*b) = make_float2(sb, sb*mub);
}

__device__ __forceinline__ float tile_phase2(const float* shb, int lane, int wv)
{
    const int i    = lane & 31;          // sample index
    const int side = lane >> 5;          // 0 = mixture A, 1 = mixture B
    const float* qp0 = shb + side*548 + (2*wv)*68;
    const float* qp1 = qp0 + 68;
    const float z0 = shb[1096 + i*17 + 2*wv];
    const float z1 = shb[1096 + i*17 + 2*wv + 1];
    float acc0 = 0.f, acc1 = 0.f;
    #pragma unroll
    for (int k = 0; k < 16; ++k) {       // j-pair per float4: {s0,smu0,s1,smu1}
        float4 f = *(const float4*)(qp0 + 4*k);
        float4 g = *(const float4*)(qp1 + 4*k);
        float e0 = fmaf(z0, f.x, -f.y); acc0 = fmaf(f.x, exp2f(-(e0*e0)), acc0);
        float e1 = fmaf(z0, f.z, -f.w); acc0 = fmaf(f.z, exp2f(-(e1*e1)), acc0);
        float e2 = fmaf(z1, g.x, -g.y); acc1 = fmaf(g.x, exp2f(-(e2*e2)), acc1);
        float e3 = fmaf(z1, g.z, -g.w); acc1 = fmaf(g.z, exp2f(-(e3*e3)), acc1);
    }
    float lg = __logf(fmaf(acc0, 0.036794063f, GKL_EPS))
             + __logf(fmaf(acc1, 0.036794063f, GKL_EPS));
    return side ? -lg : lg;
}

__global__ __launch_bounds__(256) void gkl_main(
    const float* __restrict__ muA, const float* __restrict__ lvA,
    const float* __restrict__ muB, const float* __restrict__ lvB,
    const float* __restrict__ eps, double* __restrict__ ws)
{
    __shared__ float sh[2*BUFW];

    const int bid  = blockIdx.x;         // 0..2047
    const int t    = threadIdx.x;
    const int b    = t >> 3;             // 0..31 = mixture index j
    const int wl   = t & 7;              // local pixel
    const int lane = t & 63;
    const int wv   = t >> 6;

    const int T0 = bid, T1 = bid + 2048; // T = c*32 + h*2 + wh
    const int c0 = T0 >> 5, h0 = (T0 >> 1) & 15, w0 = (T0 & 1)*8 + wl;
    const int c1 = T1 >> 5, h1 = (T1 >> 1) & 15, w1 = (T1 & 1)*8 + wl;

    TR r0, r1;
    tile_load(r0, muA, lvA, muB, lvB, eps, b, c0, h0, w0);
    tile_params(r0, sh, b, wl);
    tile_load(r1, muA, lvA, muB, lvB, eps, b, c1, h1, w1);  // in flight across barrier
    __syncthreads();

    float p0 = tile_phase2(sh, lane, wv);                   // tile1 latency hides here
    #pragma unroll
    for (int o = 32; o; o >>= 1) p0 += __shfl_xor(p0, o, 64);
    if (lane == 0) ws[T0*4 + wv] = (double)p0;

    tile_params(r1, sh + BUFW, b, wl);                      // vmcnt drain lands here
    __syncthreads();

    float p1 = tile_phase2(sh + BUFW, lane, wv);
    #pragma unroll
    for (int o = 32; o; o >>= 1) p1 += __shfl_xor(p1, o, 64);
    if (lane == 0) ws[T1*4 + wv] = (double)p1;
}

__global__ __launch_bounds__(256) void gkl_final(
    const double* __restrict__ ws, float* __restrict__ out)
{
    __shared__ double part[4];
    const int t = threadIdx.x;
    double s = 0.0;
    for (int k = t; k < 16384; k += 256) s += ws[k];
    #pragma unroll
    for (int o = 32; o; o >>= 1) s += __shfl_xor(s, o, 64);
    if ((t & 63) == 0) part[t >> 6] = s;
    __syncthreads();
    if (t == 0) out[0] = (float)(32.0 * (part[0] + part[1] + part[2] + part[3]));
}

extern "C" void kernel_launch(void* const* d_in, const int* in_sizes, int n_in,
                              void* d_out, int out_size, void* d_ws, size_t ws_size,
                              hipStream_t stream) {
    const float* muA = (const float*)d_in[0];
    const float* lvA = (const float*)d_in[1];
    const float* muB = (const float*)d_in[2];
    const float* lvB = (const float*)d_in[3];
    const float* ep  = (const float*)d_in[4];
    double* ws = (double*)d_ws;          // 16384 doubles = 128 KB
    float* out = (float*)d_out;

    gkl_main<<<2048, 256, 0, stream>>>(muA, lvA, muB, lvB, ep, ws);
    gkl_final<<<1, 256, 0, stream>>>(ws, out);
}

// Round 8
// 111.405 us; speedup vs baseline: 1.1997x; 1.1997x over previous
//
#include <hip/hip_runtime.h>

// B=32, C=128, H=W=32, kern=2 -> pooled h=w=16
// Two kernels: fused pool+params+pairwise+block-reduce, then tiny final reduce.
// out = B * sum_{i,c,h,w} [ log(mean_j dA(i,j)+eps) - log(mean_j dB(i,j)+eps) ]
//
// Per-j density folded to ONE exp2 with 3 params {mu, c2, lg2s}:
//   d_j = 1.17741002 * exp2( c2_j*(z-mu_j)^2 + lg2s_j ),  c2 = -log2e/(2v), lg2s = log2(s)
// j-loop: per 4 j's = 3 uniform ds_read_b128 (SoA float4) + 16 VALU + 4 exp2,
// all LDS reads via one base VGPR + immediate offsets.
//
// R7 change (only): ALL transcendentals use raw builtins (v_exp_f32/v_log_f32
// with no OCML denormal-fixup wrapper). Hot-loop exp2 args are <= 0 and
// underflow-to-0 is the desired semantics, so the bare instruction is exact.

#define GKL_EPS 1e-6f
#define LOG2E 1.44269504f

// LDS float layout:
//   Q: side*1540 + (g*3 + param)*64 + p*4 + e     (side 0/1, g 0..7, param 0..2)
//      param 0 = mu[4j], 1 = c2[4j], 2 = lg2s[4j]; side stride 1540 = 4-bank skew
//   zs: 3080 + b*17 + p    (padded stride 17)
//   wsum: 3624..3627
__global__ __launch_bounds__(256) void gkl_main(
    const float* __restrict__ muA, const float* __restrict__ lvA,
    const float* __restrict__ muB, const float* __restrict__ lvB,
    const float* __restrict__ eps, double* __restrict__ ws)
{
    __shared__ float sh[3628];

    const int bid = blockIdx.x;        // 0..2047 = C*16
    const int c   = bid >> 4;
    const int h   = bid & 15;
    const int t   = threadIdx.x;
    const int w   = t & 15;
    const int b0  = t >> 4;

    // ---- Phase 1: pooled params (each thread: 2 batch rows, both sides) ----
    #pragma unroll
    for (int rep = 0; rep < 2; ++rep) {
        const int b = b0 + rep*16;                         // = mixture index j
        const int base = ((b*128 + c)*32 + 2*h)*32 + 2*w;  // int addressing
        const int qw = ((b >> 2)*3)*64 + w*4 + (b & 3);    // scatter slot

        // ---- side A ----
        float2 m0 = *(const float2*)(muA + base);
        float2 m1 = *(const float2*)(muA + base + 32);
        float2 l0 = *(const float2*)(lvA + base);
        float2 l1 = *(const float2*)(lvA + base + 32);
        float mu  = (m0.x + m0.y + m1.x + m1.y) * 0.25f;
        float var = (__builtin_amdgcn_exp2f(l0.x*LOG2E) + __builtin_amdgcn_exp2f(l0.y*LOG2E)
                   + __builtin_amdgcn_exp2f(l1.x*LOG2E) + __builtin_amdgcn_exp2f(l1.y*LOG2E)) * 0.0625f;
        float c2  = -0.72134752f * __builtin_amdgcn_rcpf(var);            // -log2e/(2v)
        float ls  = fmaf(-0.5f, __builtin_amdgcn_logf(var), -0.2356196f); // log2(s)
        sh[qw]       = mu;
        sh[qw + 64]  = c2;
        sh[qw + 128] = ls;
        float ev = eps[((b*128 + c)*16 + h)*16 + w];
        sh[3080 + b*17 + w] = fmaf(__builtin_amdgcn_sqrtf(var), ev, mu);  // z

        // ---- side B ----
        float2 n0 = *(const float2*)(muB + base);
        float2 n1 = *(const float2*)(muB + base + 32);
        float2 k0 = *(const float2*)(lvB + base);
        float2 k1 = *(const float2*)(lvB + base + 32);
        float mub  = (n0.x + n0.y + n1.x + n1.y) * 0.25f;
        float varb = (__builtin_amdgcn_exp2f(k0.x*LOG2E) + __builtin_amdgcn_exp2f(k0.y*LOG2E)
                    + __builtin_amdgcn_exp2f(k1.x*LOG2E) + __builtin_amdgcn_exp2f(k1.y*LOG2E)) * 0.0625f;
        float c2b  = -0.72134752f * __builtin_amdgcn_rcpf(varb);
        float lsb  = fmaf(-0.5f, __builtin_amdgcn_logf(varb), -0.2356196f);
        sh[1540 + qw]       = mub;
        sh[1540 + qw + 64]  = c2b;
        sh[1540 + qw + 128] = lsb;
    }
    __syncthreads();

    // ---- Phase 2: wave-per-pixel, 4 j's per 3 b128 broadcasts ----
    const int lane = t & 63;
    const int wv   = t >> 6;           // wave 0..3
    const int i    = lane & 31;        // sample index
    const int side = lane >> 5;        // 0 = mixture A, 1 = mixture B
    const float* __restrict__ Qb = sh + side*1540;
    const float* __restrict__ zp = sh + 3080;
    float* __restrict__ wsum     = sh + 3624;

    float tot = 0.f;
    #pragma unroll
    for (int q = 0; q < 4; ++q) {
        const int p  = wv*4 + q;           // pixel for this wave
        const float zi = zp[i*17 + p];     // broadcast-pair across halves: free
        const float* base = Qb + p*4;      // ONE address reg; all reads imm-offset
        float accA = 0.f, accB = 0.f;
        #pragma unroll
        for (int g = 0; g < 8; ++g) {
            float4 m  = *(const float4*)(base + g*192);
            float4 cc = *(const float4*)(base + g*192 + 64);
            float4 ll = *(const float4*)(base + g*192 + 128);
            float d0 = zi - m.x, d1 = zi - m.y, d2 = zi - m.z, d3 = zi - m.w;
            accA += __builtin_amdgcn_exp2f(fmaf(d0*d0, cc.x, ll.x));
            accB += __builtin_amdgcn_exp2f(fmaf(d1*d1, cc.y, ll.y));
            accA += __builtin_amdgcn_exp2f(fmaf(d2*d2, cc.z, ll.z));
            accB += __builtin_amdgcn_exp2f(fmaf(d3*d3, cc.w, ll.w));
        }
        // 1.17741002 (=sqrt(2 ln2)) / 32
        float lg = __builtin_amdgcn_logf(fmaf(accA + accB, 0.036794063f, GKL_EPS));
        tot += side ? -lg : lg;
    }

    #pragma unroll
    for (int o = 32; o; o >>= 1) tot += __shfl_xor(tot, o, 64);
    if (lane == 0) wsum[wv] = tot;
    __syncthreads();
    if (t == 0)
        ws[bid] = (double)wsum[0] + (double)wsum[1] + (double)wsum[2] + (double)wsum[3];
}

__global__ __launch_bounds__(256) void gkl_final(
    const double* __restrict__ ws, float* __restrict__ out)
{
    __shared__ double part[4];
    const int t = threadIdx.x;
    double s = 0.0;
    for (int k = t; k < 2048; k += 256) s += ws[k];
    #pragma unroll
    for (int o = 32; o; o >>= 1) s += __shfl_xor(s, o, 64);
    if ((t & 63) == 0) part[t >> 6] = s;
    __syncthreads();
    if (t == 0) out[0] = (float)(0.69314718055994531 * 32.0 *
                                 (part[0] + part[1] + part[2] + part[3]));
}

extern "C" void kernel_launch(void* const* d_in, const int* in_sizes, int n_in,
                              void* d_out, int out_size, void* d_ws, size_t ws_size,
                              hipStream_t stream) {
    const float* muA = (const float*)d_in[0];
    const float* lvA = (const float*)d_in[1];
    const float* muB = (const float*)d_in[2];
    const float* lvB = (const float*)d_in[3];
    const float* ep  = (const float*)d_in[4];
    double* ws = (double*)d_ws;          // 2048 doubles = 16 KB
    float* out = (float*)d_out;

    gkl_main<<<2048, 256, 0, stream>>>(muA, lvA, muB, lvB, ep, ws);
    gkl_final<<<1, 256, 0, stream>>>(ws, out);
}

// Round 10
// 110.607 us; speedup vs baseline: 1.2083x; 1.0072x over previous
//
#include <hip/hip_runtime.h>

// B=32, C=128, H=W=32, kern=2 -> pooled h=w=16
// Two kernels: fused pool+params+pairwise+block-reduce, then tiny final reduce.
// out = B * sum_{i,c,h,w} [ log(mean_j dA(i,j)+eps) - log(mean_j dB(i,j)+eps) ]
//
// 2-param form: s = sqrt(log2e/2)*rsqrt(v); params {s, s*mu}:
//   d_j = (s_j/k) * exp2(-(s_j*z - s_j*mu_j)^2),  k = sqrt(log2e/2)
// j-term: fma, mul, exp2(neg-mod), fma = 3 VALU + 1 trans; 16 b128/pixel.
// 1/(32k)=0.036794063 folds into the post-sum fma; ln2 folds into the final scale.
// All transcendentals are raw builtins (bare v_exp_f32/v_log_f32): hot-loop
// exp2 args <= 0, underflow-to-0 desired; log args >= eps -> normal range.

#define GKL_EPS 1e-6f
#define LOG2E 1.44269504f

// LDS float layout:
//   Q: side*1092 + p*68 + 2j   ({s_j, s_j*mu_j}); p-stride 68 (16B-aligned,
//      +4-bank shift/pixel); side offset 1092 = +4 banks so the two half-wave
//      b128 broadcasts hit disjoint bank quads.
//   z: 2184 + i*17 + p   (17-stride: conflict-free 32-lane gather)
//   wsum: 2728..2731
__global__ __launch_bounds__(256) void gkl_main(
    const float* __restrict__ muA, const float* __restrict__ lvA,
    const float* __restrict__ muB, const float* __restrict__ lvB,
    const float* __restrict__ eps, double* __restrict__ ws)
{
    __shared__ float sh[2732];

    const int bid = blockIdx.x;        // 0..2047 = C*16
    const int c   = bid >> 4;
    const int h   = bid & 15;
    const int t   = threadIdx.x;
    const int w   = t & 15;
    const int b0  = t >> 4;

    // ---- Phase 1: pooled params (each thread: 2 batch rows, both sides) ----
    #pragma unroll
    for (int rep = 0; rep < 2; ++rep) {
        const int b = b0 + rep*16;                         // = mixture index j
        const int base = ((b*128 + c)*32 + 2*h)*32 + 2*w;

        // ---- side A ----
        float2 m0 = *(const float2*)(muA + base);
        float2 m1 = *(const float2*)(muA + base + 32);
        float2 l0 = *(const float2*)(lvA + base);
        float2 l1 = *(const float2*)(lvA + base + 32);
        float mu  = (m0.x + m0.y + m1.x + m1.y) * 0.25f;
        float var = (__builtin_amdgcn_exp2f(l0.x*LOG2E) + __builtin_amdgcn_exp2f(l0.y*LOG2E)
                   + __builtin_amdgcn_exp2f(l1.x*LOG2E) + __builtin_amdgcn_exp2f(l1.y*LOG2E)) * 0.0625f;
        float rs  = __builtin_amdgcn_rsqf(var);
        float s   = 0.84932185f * rs;                      // sqrt(log2e/2)*rsqrt(v)
        *(float2*)(sh + w*68 + 2*b) = make_float2(s, s*mu);
        float ev = eps[((b*128 + c)*16 + h)*16 + w];
        sh[2184 + b*17 + w] = fmaf(var*rs, ev, mu);        // z = mu + sqrt(v)*eps

        // ---- side B ----
        float2 n0 = *(const float2*)(muB + base);
        float2 n1 = *(const float2*)(muB + base + 32);
        float2 k0 = *(const float2*)(lvB + base);
        float2 k1 = *(const float2*)(lvB + base + 32);
        float mub  = (n0.x + n0.y + n1.x + n1.y) * 0.25f;
        float varb = (__builtin_amdgcn_exp2f(k0.x*LOG2E) + __builtin_amdgcn_exp2f(k0.y*LOG2E)
                    + __builtin_amdgcn_exp2f(k1.x*LOG2E) + __builtin_amdgcn_exp2f(k1.y*LOG2E)) * 0.0625f;
        float rsb  = __builtin_amdgcn_rsqf(varb);
        float sb   = 0.84932185f * rsb;
        *(float2*)(sh + 1092 + w*68 + 2*b) = make_float2(sb, sb*mub);
    }
    __syncthreads();

    // ---- Phase 2: wave-per-pixel-pair, 4 j-terms per 2 b128 broadcasts ----
    const int lane = t & 63;
    const int wv   = t >> 6;           // wave 0..3
    const int i    = lane & 31;        // sample index
    const int side = lane >> 5;        // 0 = mixture A, 1 = mixture B
    const float* __restrict__ Qb = sh + side*1092;
    const float* __restrict__ zp = sh + 2184;
    float* __restrict__ wsum     = sh + 2728;

    float lg = 0.f;
    #pragma unroll
    for (int q = 0; q < 2; ++q) {
        const int p0 = wv*4 + 2*q, p1 = p0 + 1;  // pixel pair for this wave
        const float z0 = zp[i*17 + p0];
        const float z1 = zp[i*17 + p1];
        const float* qp0 = Qb + p0*68;           // one addr reg, imm offsets
        const float* qp1 = Qb + p1*68;
        float acc0 = 0.f, acc1 = 0.f;
        #pragma unroll
        for (int k = 0; k < 16; ++k) {           // j-pair per float4: {s0,smu0,s1,smu1}
            float4 f = *(const float4*)(qp0 + 4*k);
            float4 g = *(const float4*)(qp1 + 4*k);
            float e0 = fmaf(z0, f.x, -f.y);
            acc0 = fmaf(f.x, __builtin_amdgcn_exp2f(-(e0*e0)), acc0);
            float e1 = fmaf(z0, f.z, -f.w);
            acc0 = fmaf(f.z, __builtin_amdgcn_exp2f(-(e1*e1)), acc0);
            float e2 = fmaf(z1, g.x, -g.y);
            acc1 = fmaf(g.x, __builtin_amdgcn_exp2f(-(e2*e2)), acc1);
            float e3 = fmaf(z1, g.z, -g.w);
            acc1 = fmaf(g.z, __builtin_amdgcn_exp2f(-(e3*e3)), acc1);
        }
        lg += __builtin_amdgcn_logf(fmaf(acc0, 0.036794063f, GKL_EPS))
            + __builtin_amdgcn_logf(fmaf(acc1, 0.036794063f, GKL_EPS));
    }
    float tot = side ? -lg : lg;

    #pragma unroll
    for (int o = 32; o; o >>= 1) tot += __shfl_xor(tot, o, 64);
    if (lane == 0) wsum[wv] = tot;
    __syncthreads();
    if (t == 0)
        ws[bid] = (double)wsum[0] + (double)wsum[1] + (double)wsum[2] + (double)wsum[3];
}

__global__ __launch_bounds__(256) void gkl_final(
    const double* __restrict__ ws, float* __restrict__ out)
{
    __shared__ double part[4];
    const int t = threadIdx.x;
    double s = 0.0;
    for (int k = t; k < 2048; k += 256) s += ws[k];
    #pragma unroll
    for (int o = 32; o; o >>= 1) s += __shfl_xor(s, o, 64);
    if ((t & 63) == 0) part[t >> 6] = s;
    __syncthreads();
    // ln2 (log2 -> ln) and the B=32 outer factor fold here
    if (t == 0) out[0] = (float)(0.69314718055994531 * 32.0 *
                                 (part[0] + part[1] + part[2] + part[3]));
}

extern "C" void kernel_launch(void* const* d_in, const int* in_sizes, int n_in,
                              void* d_out, int out_size, void* d_ws, size_t ws_size,
                              hipStream_t stream) {
    const float* muA = (const float*)d_in[0];
    const float* lvA = (const float*)d_in[1];
    const float* muB = (const float*)d_in[2];
    const float* lvB = (const float*)d_in[3];
    const float* ep  = (const float*)d_in[4];
    double* ws = (double*)d_ws;          // 2048 doubles = 16 KB
    float* out = (float*)d_out;

    gkl_main<<<2048, 256, 0, stream>>>(muA, lvA, muB, lvB, ep, ws);
    gkl_final<<<1, 256, 0, stream>>>(ws, out);
}